// Round 2
// baseline (93.221 us; speedup 1.0000x reference)
//
#include <hip/hip_runtime.h>
#include <math.h>

#define WG 256

// Branch-free symmetric 3x3 eigenvalues, ascending.
// Reduced problem: eigs of C=(A-qI)/p satisfy x^3 - 3x - 2r = 0, r=det(C)/2,
// |r|<=1, roots x = 2cos(acos(r)/3 + 2pi k/3) in [-2,2].
// Instead of trig: Newton on the sign-folded simple root, then deflate.
__device__ __forceinline__ void eig3_sym(float a00, float a11, float a22,
                                         float a01, float a02, float a12,
                                         float& e0, float& e1, float& e2) {
    const float third = 1.0f / 3.0f;
    float p1 = a01 * a01 + a02 * a02 + a12 * a12;
    float q  = (a00 + a11 + a22) * third;
    float b00 = a00 - q, b11 = a11 - q, b22 = a22 - q;
    float p2 = b00 * b00 + b11 * b11 + b22 * b22 + 2.0f * p1;
    float p2_6 = p2 * (1.0f / 6.0f);
    float invp = 0.0f, p = 0.0f;
    if (p2_6 > 0.0f) {
        invp = __builtin_amdgcn_rsqf(p2_6);   // v_rsq_f32, ~1 ulp
        p = p2_6 * invp;                      // sqrt(p2/6)
    }
    // det(A - qI)
    float det = b00 * (b11 * b22 - a12 * a12)
              - a01 * (a01 * b22 - a12 * a02)
              + a02 * (a01 * a12 - b11 * a02);
    float r = 0.5f * det * invp * invp * invp;
    r = fminf(1.0f, fmaxf(-1.0f, r));

    // Solve y^3 - 3y = 2t, t=|r|, root y in [sqrt(3), 2] (always simple:
    // f' = 3y^2-3 in [6,9]). Cubic-Hermite guess (err ~5e-4) + 2 Newton.
    float t = fabsf(r);
    float y = 1.7320508f + t * (0.33333333f + t * (-0.0850412f + t * 0.0196571f));
#pragma unroll
    for (int it = 0; it < 2; ++it) {
        float y2 = y * y;
        float fy = y * (y2 - 3.0f) - 2.0f * t;
        float fp = 3.0f * y2 - 3.0f;
        y = y - fy * __builtin_amdgcn_rcpf(fp);   // v_rcp_f32
    }
    float xa = (r >= 0.0f) ? y : -y;
    // Deflated quadratic: other two roots = (-xa +/- sqrt(12 - 3 xa^2)) / 2.
    // The sqrt recovers the near-double pair with full accuracy.
    float dd = fmaxf(12.0f - 3.0f * xa * xa, 0.0f);
    float dlt = __builtin_amdgcn_sqrtf(dd);
    float xb = 0.5f * (-xa + dlt);
    float xc = 0.5f * (-xa - dlt);

    float xmin = fminf(fminf(xa, xb), xc);
    float xmax = fmaxf(fmaxf(xa, xb), xc);
    float xmid = fmaxf(fminf(xa, xb), fminf(fmaxf(xa, xb), xc));  // med3

    e0 = fmaf(p, xmin, q);
    e1 = fmaf(p, xmid, q);
    e2 = fmaf(p, xmax, q);
}

// One thread handles 4 consecutive voxels: float4 load per channel plane,
// float4 store per eigenvalue plane. All accesses 16B-aligned & coalesced.
__global__ __launch_bounds__(WG) void eigvals_kernel(const float* __restrict__ X,
                                                     float* __restrict__ out,
                                                     int nv /* n/4 */,
                                                     long long n) {
    int tid = blockIdx.x * WG + threadIdx.x;
    int total = 2 * nv;  // b = 2
    if (tid >= total) return;
    int b = (tid >= nv) ? 1 : 0;
    int j = tid - b * nv;

    const float* src = X + (long long)b * 9 * n + 4LL * j;
    float4 m[9];
#pragma unroll
    for (int c = 0; c < 9; ++c)
        m[c] = *(const float4*)(src + (long long)c * n);

    float4 o0, o1, o2;
    float* p0 = (float*)&o0;
    float* p1 = (float*)&o1;
    float* p2 = (float*)&o2;
#pragma unroll
    for (int k = 0; k < 4; ++k) {
        float a00 = ((const float*)&m[0])[k];
        float a01 = ((const float*)&m[1])[k];
        float a02 = ((const float*)&m[2])[k];
        float a10 = ((const float*)&m[3])[k];
        float a11 = ((const float*)&m[4])[k];
        float a12 = ((const float*)&m[5])[k];
        float a20 = ((const float*)&m[6])[k];
        float a21 = ((const float*)&m[7])[k];
        float a22 = ((const float*)&m[8])[k];
        float s01 = 0.5f * (a01 + a10);
        float s02 = 0.5f * (a02 + a20);
        float s12 = 0.5f * (a12 + a21);
        eig3_sym(a00, a11, a22, s01, s02, s12, p0[k], p1[k], p2[k]);
    }

    float* dst = out + (long long)b * 3 * n + 4LL * j;
    *(float4*)(dst)         = o0;
    *(float4*)(dst + n)     = o1;
    *(float4*)(dst + 2 * n) = o2;
}

extern "C" void kernel_launch(void* const* d_in, const int* in_sizes, int n_in,
                              void* d_out, int out_size, void* d_ws, size_t ws_size,
                              hipStream_t stream) {
    const float* X = (const float*)d_in[0];
    float* out = (float*)d_out;
    long long n = (long long)in_sizes[0] / 18;  // b=2, 9 channels
    int nv = (int)(n / 4);
    int total = 2 * nv;
    int blocks = (total + WG - 1) / WG;
    eigvals_kernel<<<blocks, WG, 0, stream>>>(X, out, nv, n);
}